// Round 4
// baseline (918.795 us; speedup 1.0000x reference)
//
#include <hip/hip_runtime.h>
#include <math.h>

#define N_LEVELS 16
#define LOG2_T 19
#define TABLE_SIZE (1 << LOG2_T)

typedef float v4f __attribute__((ext_vector_type(4)));

struct ResTable { float r[N_LEVELS]; };

// One thread per point; loop over the 16 levels in temporal lockstep
// (__syncthreads per level) so the whole GPU touches ~1 table at a time and
// each XCD's 4 MiB L2 keeps the current 4 MiB table resident.
// Output: thread writes its point's 32 floats (128 B) with nontemporal v4f
// stores so the write-only output doesn't evict table lines from L2.
__global__ __launch_bounds__(256, 4) void ingp_hash_kernel(
    const float* __restrict__ x,
    const float* __restrict__ emb,
    float* __restrict__ out,
    int n_pts,
    ResTable res)
{
    int t = blockIdx.x * blockDim.x + threadIdx.x;
    // Out-of-range threads do redundant work on the last point (but don't
    // store) so every thread reaches the per-level __syncthreads.
    bool live = t < n_pts;
    int n = live ? t : (n_pts - 1);

    // clip to [-1, 1]
    float xx = fminf(fmaxf(x[n * 3 + 0], -1.0f), 1.0f);
    float xy = fminf(fmaxf(x[n * 3 + 1], -1.0f), 1.0f);
    float xz = fminf(fmaxf(x[n * 3 + 2], -1.0f), 1.0f);

    float acc[2 * N_LEVELS];

#pragma unroll
    for (int lvl = 0; lvl < N_LEVELS; ++lvl) {
        float r = res.r[lvl];
        float grid = 2.0f / r;  // fp32 IEEE div == numpy

        // bottom-left voxel index: floor((x - BOX_MIN) / grid) — bit-exact
        // integer path: add, div, floor only.
        int blx = (int)floorf((xx + 1.0f) / grid);
        int bly = (int)floorf((xy + 1.0f) / grid);
        int blz = (int)floorf((xz + 1.0f) / grid);

        // trilinear weights w = (x - vmin) / grid, vmin = bl*grid + BOX_MIN
        float wx = (xx - ((float)blx * grid + -1.0f)) / grid;
        float wy = (xy - ((float)bly * grid + -1.0f)) / grid;
        float wz = (xz - ((float)blz * grid + -1.0f)) / grid;

        const float* __restrict__ table = emb + (size_t)lvl * (TABLE_SIZE * 2);

        float a0 = 0.0f, a1 = 0.0f;
#pragma unroll
        for (int k = 0; k < 8; ++k) {
            // OFFSETS bit order: x = k>>2, y = k>>1, z = k
            int bx = (k >> 2) & 1;
            int by = (k >> 1) & 1;
            int bz = k & 1;
            unsigned cx = (unsigned)(blx + bx);
            unsigned cy = (unsigned)(bly + by);
            unsigned cz = (unsigned)(blz + bz);
            unsigned h = cx ^ (cy * 2654435761u) ^ (cz * 805459861u);
            unsigned idx = h & (unsigned)(TABLE_SIZE - 1);
            float2 e = *(const float2*)(table + (size_t)idx * 2);
            float fx = bx ? wx : 1.0f - wx;
            float fy = by ? wy : 1.0f - wy;
            float fz = bz ? wz : 1.0f - wz;
            float wgt = (fx * fy) * fz;
            a0 += wgt * e.x;
            a1 += wgt * e.y;
        }
        acc[2 * lvl + 0] = a0;
        acc[2 * lvl + 1] = a1;

        // Keep the block's 4 waves in level-lockstep for L2 temporal locality.
        __syncthreads();
    }

    if (live) {
        v4f* o = (v4f*)(out + (size_t)t * (2 * N_LEVELS));
#pragma unroll
        for (int j = 0; j < 8; ++j) {
            v4f v = {acc[4 * j + 0], acc[4 * j + 1],
                     acc[4 * j + 2], acc[4 * j + 3]};
            __builtin_nontemporal_store(v, o + j);
        }
    }
}

extern "C" void kernel_launch(void* const* d_in, const int* in_sizes, int n_in,
                              void* d_out, int out_size, void* d_ws, size_t ws_size,
                              hipStream_t stream) {
    const float* x   = (const float*)d_in[0];
    const float* emb = (const float*)d_in[1];
    float* out = (float*)d_out;
    int n_pts = in_sizes[0] / 3;

    // RESOLUTIONS: replicate numpy float64 semantics on host (same libm):
    // b = exp((log(512) - log(16)) / 15); res_i = float32(floor(16 * b**i))
    ResTable res;
    double b = exp((log(512.0) - log(16.0)) / 15.0);
    for (int i = 0; i < N_LEVELS; ++i) {
        res.r[i] = (float)floor(16.0 * pow(b, (double)i));
    }

    int threads = 256;
    int blocks = (n_pts + threads - 1) / threads;
    hipLaunchKernelGGL(ingp_hash_kernel, dim3(blocks), dim3(threads), 0, stream,
                       x, emb, out, n_pts, res);
}

// Round 5
// 807.184 us; speedup vs baseline: 1.1383x; 1.1383x over previous
//
#include <hip/hip_runtime.h>
#include <math.h>

#define N_LEVELS 16
#define LOG2_T 19
#define TABLE_SIZE (1 << LOG2_T)

typedef float v4f __attribute__((ext_vector_type(4)));

struct ResTable { float r[N_LEVELS]; };

// One thread per (point, level-pair): lp = t & 7 -> levels {2lp, 2lp+1},
// n = t >> 3. All 16 hash indices are computed first, then all 16 float2
// gathers are issued into an array before any use -> ~16 outstanding
// cache-misses per thread (R1 had VGPR_Count=20, which serialized the
// gathers to ~2-3 in flight; this kernel is latency-limited, not BW-limited).
// Output: one contiguous float4 per thread at out + n*32 + lp*4 -> each wave
// stores 1 KiB contiguous (8 points x 128 B). No nontemporal (R4 lesson:
// evict-early on partial lines inflated WRITE_SIZE 2.7x).
__global__ __launch_bounds__(256) void ingp_hash_kernel(
    const float* __restrict__ x,
    const float* __restrict__ emb,
    float* __restrict__ out,
    int n_pts,
    ResTable res)
{
    int t = blockIdx.x * blockDim.x + threadIdx.x;
    int lp = t & 7;
    int n = t >> 3;
    if (n >= n_pts) return;

    // clip to [-1, 1]
    float xx = fminf(fmaxf(x[n * 3 + 0], -1.0f), 1.0f);
    float xy = fminf(fmaxf(x[n * 3 + 1], -1.0f), 1.0f);
    float xz = fminf(fmaxf(x[n * 3 + 2], -1.0f), 1.0f);

    unsigned voff[16];   // float-offsets into emb for all 16 gathers
    float w[2][3];       // trilinear weights per level

#pragma unroll
    for (int j = 0; j < 2; ++j) {
        int lvl = 2 * lp + j;
        float r = res.r[lvl];
        float grid = 2.0f / r;  // fp32 IEEE div == numpy

        // bottom-left voxel index: floor((x - BOX_MIN) / grid) — bit-exact
        // integer path: add, div, floor only (no contractable FMA).
        int blx = (int)floorf((xx + 1.0f) / grid);
        int bly = (int)floorf((xy + 1.0f) / grid);
        int blz = (int)floorf((xz + 1.0f) / grid);

        // w = (x - vmin) / grid, vmin = bl*grid + BOX_MIN
        w[j][0] = (xx - ((float)blx * grid + -1.0f)) / grid;
        w[j][1] = (xy - ((float)bly * grid + -1.0f)) / grid;
        w[j][2] = (xz - ((float)blz * grid + -1.0f)) / grid;

        unsigned lbase = (unsigned)lvl << 20;  // lvl * TABLE_SIZE * 2 floats
#pragma unroll
        for (int k = 0; k < 8; ++k) {
            // OFFSETS bit order: x = k>>2, y = k>>1, z = k
            unsigned cx = (unsigned)(blx + ((k >> 2) & 1));
            unsigned cy = (unsigned)(bly + ((k >> 1) & 1));
            unsigned cz = (unsigned)(blz + (k & 1));
            unsigned h = cx ^ (cy * 2654435761u) ^ (cz * 805459861u);
            unsigned idx = h & (unsigned)(TABLE_SIZE - 1);
            voff[8 * j + k] = lbase + (idx << 1);
        }
    }

    // Issue all 16 gathers before consuming any result.
    float2 e[16];
#pragma unroll
    for (int i = 0; i < 16; ++i) {
        e[i] = *(const float2*)(emb + voff[i]);
    }

    float a[4];  // (f0,f1) for level 2lp, then level 2lp+1
#pragma unroll
    for (int j = 0; j < 2; ++j) {
        float wx = w[j][0], wy = w[j][1], wz = w[j][2];
        float a0 = 0.0f, a1 = 0.0f;
#pragma unroll
        for (int k = 0; k < 8; ++k) {
            float fx = ((k >> 2) & 1) ? wx : 1.0f - wx;
            float fy = ((k >> 1) & 1) ? wy : 1.0f - wy;
            float fz = (k & 1) ? wz : 1.0f - wz;
            float wgt = (fx * fy) * fz;
            a0 += wgt * e[8 * j + k].x;
            a1 += wgt * e[8 * j + k].y;
        }
        a[2 * j + 0] = a0;
        a[2 * j + 1] = a1;
    }

    v4f v = {a[0], a[1], a[2], a[3]};
    *(v4f*)(out + (size_t)n * (2 * N_LEVELS) + 4 * lp) = v;
}

extern "C" void kernel_launch(void* const* d_in, const int* in_sizes, int n_in,
                              void* d_out, int out_size, void* d_ws, size_t ws_size,
                              hipStream_t stream) {
    const float* x   = (const float*)d_in[0];
    const float* emb = (const float*)d_in[1];
    float* out = (float*)d_out;
    int n_pts = in_sizes[0] / 3;

    // RESOLUTIONS: replicate numpy float64 semantics on host (same libm):
    // b = exp((log(512) - log(16)) / 15); res_i = float32(floor(16 * b**i))
    ResTable res;
    double b = exp((log(512.0) - log(16.0)) / 15.0);
    for (int i = 0; i < N_LEVELS; ++i) {
        res.r[i] = (float)floor(16.0 * pow(b, (double)i));
    }

    long long total = (long long)n_pts * 8;  // one thread per (point, level-pair)
    int threads = 256;
    int blocks = (int)((total + threads - 1) / threads);
    hipLaunchKernelGGL(ingp_hash_kernel, dim3(blocks), dim3(threads), 0, stream,
                       x, emb, out, n_pts, res);
}